// Round 1
// baseline (579.599 us; speedup 1.0000x reference)
//
#include <hip/hip_runtime.h>
#include <math.h>

// Problem constants (reference: N=8192, D=128, NUM_CLASSES=128)
#define TS 64          // pass1 tile size
#define NBINS 256      // label histogram bins (labels are < 128; 256 for safety)

// ---------------------------------------------------------------------------
// Kernel 1: row normalization. y_i = x_i / (||x_i|| * sqrt(T))
// One 64-thread block per row, D=128 -> float2 per lane.
__global__ __launch_bounds__(64) void norm_kernel(
    const float* __restrict__ X, float* __restrict__ Y, float inv_sqrtT) {
  int row = blockIdx.x;
  const float2* x = (const float2*)(X + (size_t)row * 128);
  float2 v = x[threadIdx.x];
  float s = v.x * v.x + v.y * v.y;
#pragma unroll
  for (int m = 1; m < 64; m <<= 1) s += __shfl_xor(s, m);
  float inv = inv_sqrtT * rsqrtf(fmaxf(s, 1e-24f));
  float2 o;
  o.x = v.x * inv;
  o.y = v.y * inv;
  ((float2*)(Y + (size_t)row * 128))[threadIdx.x] = o;
}

// ---------------------------------------------------------------------------
// Kernel 2: label histogram
__global__ __launch_bounds__(256) void hist_kernel(
    const int* __restrict__ lab, int* __restrict__ cnt, int N) {
  int i = blockIdx.x * 256 + threadIdx.x;
  if (i < N) atomicAdd(&cnt[lab[i] & (NBINS - 1)], 1);
}

// Kernel 3: exclusive scan over 256 bins + n_pos (single thread; trivial size)
__global__ void scan_kernel(const int* __restrict__ cnt, int* __restrict__ offs,
                            int* __restrict__ cursor, float* __restrict__ accum,
                            int N) {
  int off = 0;
  long long np = 0;
  for (int c = 0; c < NBINS; ++c) {
    offs[c] = off;
    cursor[c] = off;
    int m = cnt[c];
    off += m;
    np += (long long)m * m;
  }
  accum[1] = (float)(np - N);  // n_pos
}

// Kernel 4: scatter indices into label-grouped order
__global__ __launch_bounds__(256) void scatter_kernel(
    const int* __restrict__ lab, int* __restrict__ cursor,
    int* __restrict__ sorted, int N) {
  int i = blockIdx.x * 256 + threadIdx.x;
  if (i < N) {
    int p = atomicAdd(&cursor[lab[i] & (NBINS - 1)], 1);
    sorted[p] = i;
  }
}

// ---------------------------------------------------------------------------
// Kernel 5 (the heavy one): S = Y*Y^T tile, fused exp + label mask + row sum.
// unsim[i] += sum_{j in tile, lab[j] != lab[i]} exp(dot(y_i, y_j))
// 64x64 tile, 256 threads = 16x16 grid, 4x4 accumulators per thread.
// LDS: A/B tiles stored as float4 with XOR-swizzled k-index -> <=2-way bank
// conflicts on both staging writes and compute reads.
__global__ __launch_bounds__(256) void pass1_kernel(
    const float* __restrict__ Y, const int* __restrict__ lab,
    float* __restrict__ unsim) {
  __shared__ float4 As4[TS * 32];  // [row][kq^swz]  (32 float4 per row, K=128)
  __shared__ float4 Bs4[TS * 32];
  __shared__ int labR[TS], labC[TS];

  const int t = threadIdx.x;
  const int tx = t & 15, ty = t >> 4;
  const int i0 = blockIdx.y * TS, j0 = blockIdx.x * TS;

  const float4* Yg = (const float4*)Y;  // row stride = 32 float4
  for (int f = t; f < TS * 32; f += 256) {
    int row = f >> 5, kq = f & 31;
    int sw = kq ^ ((row >> 2) & 7);
    As4[row * 32 + sw] = Yg[(size_t)(i0 + row) * 32 + kq];
    Bs4[row * 32 + sw] = Yg[(size_t)(j0 + row) * 32 + kq];
  }
  if (t < TS) {
    labR[t] = lab[i0 + t];
    labC[t] = lab[j0 + t];
  }
  __syncthreads();

  float acc[4][4] = {};
  const int aswz = ty & 7, bswz = tx & 7;
#pragma unroll 8
  for (int kk = 0; kk < 32; ++kk) {
    float4 a[4], b[4];
#pragma unroll
    for (int r = 0; r < 4; ++r) a[r] = As4[(4 * ty + r) * 32 + (kk ^ aswz)];
#pragma unroll
    for (int c = 0; c < 4; ++c) b[c] = Bs4[(4 * tx + c) * 32 + (kk ^ bswz)];
#pragma unroll
    for (int r = 0; r < 4; ++r)
#pragma unroll
      for (int c = 0; c < 4; ++c) {
        acc[r][c] += a[r].x * b[c].x;
        acc[r][c] += a[r].y * b[c].y;
        acc[r][c] += a[r].z * b[c].z;
        acc[r][c] += a[r].w * b[c].w;
      }
  }

  // Epilogue: masked exp row-sums (negatives only)
  int lr[4], lc[4];
#pragma unroll
  for (int r = 0; r < 4; ++r) lr[r] = labR[4 * ty + r];
#pragma unroll
  for (int c = 0; c < 4; ++c) lc[c] = labC[4 * tx + c];

  float rs[4] = {0.f, 0.f, 0.f, 0.f};
#pragma unroll
  for (int r = 0; r < 4; ++r)
#pragma unroll
    for (int c = 0; c < 4; ++c)
      if (lr[r] != lc[c]) rs[r] += __expf(acc[r][c]);

  // reduce across the 16 tx lanes (all within one wave: lane = (ty%4)*16+tx)
#pragma unroll
  for (int m = 1; m < 16; m <<= 1) {
#pragma unroll
    for (int r = 0; r < 4; ++r) rs[r] += __shfl_xor(rs[r], m);
  }
  if (tx == 0) {
#pragma unroll
    for (int r = 0; r < 4; ++r) atomicAdd(&unsim[i0 + 4 * ty + r], rs[r]);
  }
}

// ---------------------------------------------------------------------------
// Kernel 6: positive pairs. One block per label class; iterate m*m pairs.
// term = log(exp(s) + unsim[a]) - s
__global__ __launch_bounds__(256) void pass2_kernel(
    const float* __restrict__ Y, const int* __restrict__ sorted,
    const int* __restrict__ cnt, const int* __restrict__ offs,
    const float* __restrict__ unsim, float* __restrict__ accum) {
  int c = blockIdx.x;
  int m = cnt[c];
  int off = offs[c];
  float local = 0.f;
  if (m > 1) {
    int total = m * m;
    for (int p = threadIdx.x; p < total; p += 256) {
      int pi = p / m;
      int pj = p - pi * m;
      if (pi == pj) continue;
      int a = sorted[off + pi];
      int b = sorted[off + pj];
      const float4* ya = (const float4*)(Y + (size_t)a * 128);
      const float4* yb = (const float4*)(Y + (size_t)b * 128);
      float s = 0.f;
#pragma unroll
      for (int q = 0; q < 32; ++q) {
        float4 u = ya[q], v = yb[q];
        s += u.x * v.x + u.y * v.y + u.z * v.z + u.w * v.w;
      }
      local += logf(__expf(s) + unsim[a]) - s;
    }
  }
  // block reduce (4 waves)
  __shared__ float red[4];
#pragma unroll
  for (int msk = 1; msk < 64; msk <<= 1) local += __shfl_xor(local, msk);
  int lane = threadIdx.x & 63, w = threadIdx.x >> 6;
  if (lane == 0) red[w] = local;
  __syncthreads();
  if (threadIdx.x == 0) {
    atomicAdd(&accum[0], red[0] + red[1] + red[2] + red[3]);
  }
}

// Kernel 7: finalize
__global__ void finalize_kernel(const float* __restrict__ accum,
                                float* __restrict__ out) {
  out[0] = accum[0] / accum[1];
}

// ---------------------------------------------------------------------------
extern "C" void kernel_launch(void* const* d_in, const int* in_sizes, int n_in,
                              void* d_out, int out_size, void* d_ws,
                              size_t ws_size, hipStream_t stream) {
  const float* X = (const float*)d_in[0];
  const int* lab = (const int*)d_in[1];
  float* out = (float*)d_out;

  const int N = in_sizes[1];        // 8192
  // D is fixed at 128 by the reference shapes.

  // Workspace layout
  float* Y = (float*)d_ws;               // N*128 floats
  float* unsim = Y + (size_t)N * 128;    // N floats
  float* accum = unsim + N;              // 2 floats: loss_sum, n_pos
  int* cnt = (int*)(accum + 2);          // NBINS
  int* cursor = cnt + NBINS;             // NBINS
  int* offs = cursor + NBINS;            // NBINS
  int* sorted = offs + NBINS;            // N

  // zero: unsim + accum + cnt (contiguous region)
  hipMemsetAsync(unsim, 0, (size_t)(N + 2 + NBINS) * sizeof(float), stream);

  const float inv_sqrtT = 2.2360679775f;  // 1/sqrt(0.2)
  norm_kernel<<<N, 64, 0, stream>>>(X, Y, inv_sqrtT);
  hist_kernel<<<(N + 255) / 256, 256, 0, stream>>>(lab, cnt, N);
  scan_kernel<<<1, 1, 0, stream>>>(cnt, offs, cursor, accum, N);
  scatter_kernel<<<(N + 255) / 256, 256, 0, stream>>>(lab, cursor, sorted, N);

  dim3 grid(N / TS, N / TS);
  pass1_kernel<<<grid, 256, 0, stream>>>(Y, lab, unsim);
  pass2_kernel<<<NBINS, 256, 0, stream>>>(Y, sorted, cnt, offs, unsim, accum);
  finalize_kernel<<<1, 1, 0, stream>>>(accum, out);
}

// Round 2
// 243.345 us; speedup vs baseline: 2.3818x; 2.3818x over previous
//
#include <hip/hip_runtime.h>
#include <math.h>

#define NBINS 256  // label bins (labels < 128; 256 for safety)

typedef _Float16 half8 __attribute__((ext_vector_type(8)));
typedef _Float16 half2v __attribute__((ext_vector_type(2)));
typedef float f32x4 __attribute__((ext_vector_type(4)));

// ---------------------------------------------------------------------------
// Kernel 1: row normalization. y_i = x_i / (||x_i|| * sqrt(T)); writes fp32
// copy (for exact positive-pair dots) and f16 copy (for MFMA pass1).
__global__ __launch_bounds__(64) void norm_kernel(
    const float* __restrict__ X, float* __restrict__ Yf,
    _Float16* __restrict__ Yh, float inv_sqrtT) {
  int row = blockIdx.x;
  float2 v = ((const float2*)(X + (size_t)row * 128))[threadIdx.x];
  float s = v.x * v.x + v.y * v.y;
#pragma unroll
  for (int m = 1; m < 64; m <<= 1) s += __shfl_xor(s, m);
  float inv = inv_sqrtT * rsqrtf(fmaxf(s, 1e-24f));
  float2 o;
  o.x = v.x * inv;
  o.y = v.y * inv;
  ((float2*)(Yf + (size_t)row * 128))[threadIdx.x] = o;
  half2v h;
  h.x = (_Float16)o.x;
  h.y = (_Float16)o.y;
  ((half2v*)(Yh + (size_t)row * 128))[threadIdx.x] = h;
}

// ---------------------------------------------------------------------------
// Kernel 2: label histogram
__global__ __launch_bounds__(256) void hist_kernel(
    const int* __restrict__ lab, int* __restrict__ cnt, int N) {
  int i = blockIdx.x * 256 + threadIdx.x;
  if (i < N) atomicAdd(&cnt[lab[i] & (NBINS - 1)], 1);
}

// Kernel 3: parallel exclusive scan over 256 bins + n_pos (one 256-thr block)
__global__ __launch_bounds__(256) void scan_kernel(
    const int* __restrict__ cnt, int* __restrict__ offs,
    int* __restrict__ cursor, float* __restrict__ accum, int N) {
  __shared__ int wtot[4];
  __shared__ float stot[4];
  int t = threadIdx.x;
  int lane = t & 63, w = t >> 6;
  int c = cnt[t];
  // inclusive scan within wave
  int x = c;
#pragma unroll
  for (int d = 1; d < 64; d <<= 1) {
    int y = __shfl_up(x, d);
    if (lane >= d) x += y;
  }
  if (lane == 63) wtot[w] = x;
  // n_pos partial
  float s = (float)c * (float)c;
#pragma unroll
  for (int d = 1; d < 64; d <<= 1) s += __shfl_xor(s, d);
  if (lane == 0) stot[w] = s;
  __syncthreads();
  int base = 0;
  for (int i = 0; i < w; ++i) base += wtot[i];
  int excl = base + x - c;
  offs[t] = excl;
  cursor[t] = excl;
  if (t == 0) accum[1] = stot[0] + stot[1] + stot[2] + stot[3] - (float)N;
}

// Kernel 4: scatter indices into label-grouped order
__global__ __launch_bounds__(256) void scatter_kernel(
    const int* __restrict__ lab, int* __restrict__ cursor,
    int* __restrict__ sorted, int N) {
  int i = blockIdx.x * 256 + threadIdx.x;
  if (i < N) {
    int p = atomicAdd(&cursor[lab[i] & (NBINS - 1)], 1);
    sorted[p] = i;
  }
}

// ---------------------------------------------------------------------------
// Kernel 5: MFMA similarity pass, upper-triangular tile pairs, fused
// exp + label-mask + row/col sums into unsim. 128x128 tile, 4 waves, each
// wave owns a 64x64 quadrant built from 4x4 grid of 16x16x32 f16 MFMAs.
__global__ __launch_bounds__(256, 2) void pass1_kernel(
    const _Float16* __restrict__ Yh, const int* __restrict__ lab,
    float* __restrict__ unsim, int nt) {
  __shared__ _Float16 As[128][136];  // +8 halves pad: <=2-way LDS conflicts
  __shared__ _Float16 Bs[128][136];
  __shared__ int labR[128], labC[128];
  __shared__ float rsumS[128], csumS[128];

  // decode linear block id -> (bi, bj), bi <= bj
  int b = blockIdx.x;
  float ntf = (float)nt;
  int bi = (int)((2.f * ntf + 1.f -
                  sqrtf((2.f * ntf + 1.f) * (2.f * ntf + 1.f) - 8.f * (float)b)) *
                 0.5f);
  if (bi < 0) bi = 0;
  while ((bi + 1) * nt - ((bi + 1) * bi) / 2 <= b) ++bi;
  while (bi * nt - (bi * (bi - 1)) / 2 > b) --bi;
  int bj = bi + (b - (bi * nt - (bi * (bi - 1)) / 2));
  const int i0 = bi * 128, j0 = bj * 128;

  const int t = threadIdx.x;
  // stage tiles (16B chunks; Y row = 16 chunks)
  const float4* Yg = (const float4*)Yh;
  for (int c = t; c < 128 * 16; c += 256) {
    int row = c >> 4, kc = c & 15;
    ((float4*)&As[row][0])[kc] = Yg[(size_t)(i0 + row) * 16 + kc];
    ((float4*)&Bs[row][0])[kc] = Yg[(size_t)(j0 + row) * 16 + kc];
  }
  if (t < 128) {
    labR[t] = lab[i0 + t];
    labC[t] = lab[j0 + t];
    rsumS[t] = 0.f;
    csumS[t] = 0.f;
  }
  __syncthreads();

  const int w = t >> 6, lane = t & 63;
  const int quad = lane >> 4, l16 = lane & 15;
  const int rbase = (w >> 1) * 64, cbase = (w & 1) * 64;

  f32x4 acc[4][4] = {};
#pragma unroll
  for (int ks = 0; ks < 4; ++ks) {
    const int kof = ks * 32 + quad * 8;
    half8 af[4], bf[4];
#pragma unroll
    for (int p = 0; p < 4; ++p)
      af[p] = *(const half8*)&As[rbase + p * 16 + l16][kof];
#pragma unroll
    for (int p = 0; p < 4; ++p)
      bf[p] = *(const half8*)&Bs[cbase + p * 16 + l16][kof];
#pragma unroll
    for (int pi = 0; pi < 4; ++pi)
#pragma unroll
      for (int pj = 0; pj < 4; ++pj)
        acc[pi][pj] = __builtin_amdgcn_mfma_f32_16x16x32_f16(
            af[pi], bf[pj], acc[pi][pj], 0, 0, 0);
  }

  // epilogue: masked exp, row sums (this band) + col sums (mirror band)
  int lr[4][4], lc[4];
#pragma unroll
  for (int pi = 0; pi < 4; ++pi)
#pragma unroll
    for (int r = 0; r < 4; ++r) lr[pi][r] = labR[rbase + pi * 16 + quad * 4 + r];
#pragma unroll
  for (int pj = 0; pj < 4; ++pj) lc[pj] = labC[cbase + pj * 16 + l16];

  float rowp[4][4] = {};
  float colp[4] = {0.f, 0.f, 0.f, 0.f};
#pragma unroll
  for (int pi = 0; pi < 4; ++pi)
#pragma unroll
    for (int pj = 0; pj < 4; ++pj)
#pragma unroll
      for (int r = 0; r < 4; ++r) {
        float e = (lr[pi][r] != lc[pj]) ? __expf(acc[pi][pj][r]) : 0.f;
        rowp[pi][r] += e;
        colp[pj] += e;
      }

  // row sums: reduce across the 16 lanes of each quad (cols)
#pragma unroll
  for (int pi = 0; pi < 4; ++pi)
#pragma unroll
    for (int r = 0; r < 4; ++r) {
      float v = rowp[pi][r];
      v += __shfl_xor(v, 1);
      v += __shfl_xor(v, 2);
      v += __shfl_xor(v, 4);
      v += __shfl_xor(v, 8);
      if (l16 == 0) atomicAdd(&rsumS[rbase + pi * 16 + quad * 4 + r], v);
    }
  // col sums: reduce across quads (rows)
#pragma unroll
  for (int pj = 0; pj < 4; ++pj) {
    float v = colp[pj];
    v += __shfl_xor(v, 16);
    v += __shfl_xor(v, 32);
    if (quad == 0) atomicAdd(&csumS[cbase + pj * 16 + l16], v);
  }
  __syncthreads();

  if (t < 128) {
    atomicAdd(&unsim[i0 + t], rsumS[t]);
  } else if (bi != bj) {
    atomicAdd(&unsim[j0 + (t - 128)], csumS[t - 128]);
  }
}

// ---------------------------------------------------------------------------
// Kernel 6: positive pairs (label-grouped). grid = (NBINS, CH)
__global__ __launch_bounds__(256) void pass2_kernel(
    const float* __restrict__ Yf, const int* __restrict__ sorted,
    const int* __restrict__ cnt, const int* __restrict__ offs,
    const float* __restrict__ unsim, float* __restrict__ accum) {
  int c = blockIdx.x;
  int m = cnt[c];
  int off = offs[c];
  float local = 0.f;
  if (m > 1) {
    int total = m * m;
    int stride = 256 * gridDim.y;
    for (int p = blockIdx.y * 256 + threadIdx.x; p < total; p += stride) {
      int pi = p / m;
      int pj = p - pi * m;
      if (pi == pj) continue;
      int a = sorted[off + pi];
      int bb = sorted[off + pj];
      const float4* ya = (const float4*)(Yf + (size_t)a * 128);
      const float4* yb = (const float4*)(Yf + (size_t)bb * 128);
      float s = 0.f;
#pragma unroll
      for (int q = 0; q < 32; ++q) {
        float4 u = ya[q], v = yb[q];
        s += u.x * v.x + u.y * v.y + u.z * v.z + u.w * v.w;
      }
      local += logf(__expf(s) + unsim[a]) - s;
    }
  }
  __shared__ float red[4];
#pragma unroll
  for (int msk = 1; msk < 64; msk <<= 1) local += __shfl_xor(local, msk);
  int lane = threadIdx.x & 63, w = threadIdx.x >> 6;
  if (lane == 0) red[w] = local;
  __syncthreads();
  if (threadIdx.x == 0) atomicAdd(&accum[0], red[0] + red[1] + red[2] + red[3]);
}

// Kernel 7: finalize
__global__ void finalize_kernel(const float* __restrict__ accum,
                                float* __restrict__ out) {
  out[0] = accum[0] / accum[1];
}

// ---------------------------------------------------------------------------
extern "C" void kernel_launch(void* const* d_in, const int* in_sizes, int n_in,
                              void* d_out, int out_size, void* d_ws,
                              size_t ws_size, hipStream_t stream) {
  const float* X = (const float*)d_in[0];
  const int* lab = (const int*)d_in[1];
  float* out = (float*)d_out;

  const int N = in_sizes[1];  // 8192; D fixed at 128

  // workspace layout
  float* Yf = (float*)d_ws;                        // N*128 f32
  _Float16* Yh = (_Float16*)(Yf + (size_t)N * 128);  // N*128 f16
  float* unsim = (float*)(Yh + (size_t)N * 128);   // N f32
  float* accum = unsim + N;                        // 2 f32
  int* cnt = (int*)(accum + 2);                    // NBINS
  int* cursor = cnt + NBINS;                       // NBINS
  int* offs = cursor + NBINS;                      // NBINS
  int* sorted = offs + NBINS;                      // N

  // zero unsim + accum + cnt (contiguous)
  hipMemsetAsync(unsim, 0, (size_t)(N + 2 + NBINS) * sizeof(float), stream);

  const float inv_sqrtT = 2.2360679775f;  // 1/sqrt(0.2)
  norm_kernel<<<N, 64, 0, stream>>>(X, Yf, Yh, inv_sqrtT);
  hist_kernel<<<(N + 255) / 256, 256, 0, stream>>>(lab, cnt, N);
  scan_kernel<<<1, 256, 0, stream>>>(cnt, offs, cursor, accum, N);
  scatter_kernel<<<(N + 255) / 256, 256, 0, stream>>>(lab, cursor, sorted, N);

  const int nt = N / 128;                 // 64 tiles per dim
  const int nblk = nt * (nt + 1) / 2;     // 2080 upper-tri tile pairs
  pass1_kernel<<<nblk, 256, 0, stream>>>(Yh, lab, unsim, nt);
  pass2_kernel<<<dim3(NBINS, 8), 256, 0, stream>>>(Yf, sorted, cnt, offs, unsim,
                                                   accum);
  finalize_kernel<<<1, 1, 0, stream>>>(accum, out);
}

// Round 3
// 170.725 us; speedup vs baseline: 3.3949x; 1.4254x over previous
//
#include <hip/hip_runtime.h>
#include <math.h>

#define NBINS 256   // label bins (labels < 128; 256 for safety)
#define PCAP 1024   // per-block LDS positive-pair staging capacity

typedef _Float16 half8 __attribute__((ext_vector_type(8)));
typedef _Float16 half2v __attribute__((ext_vector_type(2)));
typedef float f32x4 __attribute__((ext_vector_type(4)));

// ---------------------------------------------------------------------------
// Kernel 1: row normalization. y_i = x_i / (||x_i|| * sqrt(T)), f16 output.
__global__ __launch_bounds__(64) void norm_kernel(
    const float* __restrict__ X, _Float16* __restrict__ Yh, float inv_sqrtT) {
  int row = blockIdx.x;
  float2 v = ((const float2*)(X + (size_t)row * 128))[threadIdx.x];
  float s = v.x * v.x + v.y * v.y;
#pragma unroll
  for (int m = 1; m < 64; m <<= 1) s += __shfl_xor(s, m);
  float inv = inv_sqrtT * rsqrtf(fmaxf(s, 1e-24f));
  half2v h;
  h.x = (_Float16)(v.x * inv);
  h.y = (_Float16)(v.y * inv);
  ((half2v*)(Yh + (size_t)row * 128))[threadIdx.x] = h;
}

// ---------------------------------------------------------------------------
// Kernel 2: label histogram
__global__ __launch_bounds__(256) void hist_kernel(
    const int* __restrict__ lab, int* __restrict__ cnt, int N) {
  int i = blockIdx.x * 256 + threadIdx.x;
  if (i < N) atomicAdd(&cnt[lab[i] & (NBINS - 1)], 1);
}

// Kernel 3: n_pos = sum(m_c^2) - N (one 256-thread block)
__global__ __launch_bounds__(256) void npos_kernel(
    const int* __restrict__ cnt, float* __restrict__ accum, int N) {
  __shared__ float stot[4];
  int t = threadIdx.x;
  int lane = t & 63, w = t >> 6;
  float c = (float)cnt[t];
  float s = c * c;
#pragma unroll
  for (int d = 1; d < 64; d <<= 1) s += __shfl_xor(s, d);
  if (lane == 0) stot[w] = s;
  __syncthreads();
  if (t == 0) accum[1] = stot[0] + stot[1] + stot[2] + stot[3] - (float)N;
}

// ---------------------------------------------------------------------------
// Kernel 4: MFMA similarity pass over upper-triangular 128x128 tile pairs.
// Fused: exp + label-mask row/col sums into unsim, AND positive-pair
// (idx, s) record append (ballot-aggregated -> LDS staging -> global).
__global__ __launch_bounds__(256, 2) void pass1_kernel(
    const _Float16* __restrict__ Yh, const int* __restrict__ lab,
    float* __restrict__ unsim, uint2* __restrict__ posBuf,
    int* __restrict__ pcur, int nt) {
  __shared__ _Float16 As[128][136];  // +8 halves pad: <=2-way LDS conflicts
  __shared__ _Float16 Bs[128][136];
  __shared__ int labR[128], labC[128];
  __shared__ float rsumS[128], csumS[128];
  __shared__ uint2 posS[PCAP];
  __shared__ int posCnt, gbaseS;

  // decode linear block id -> (bi, bj), bi <= bj
  int b = blockIdx.x;
  float ntf = (float)nt;
  int bi = (int)((2.f * ntf + 1.f -
                  sqrtf((2.f * ntf + 1.f) * (2.f * ntf + 1.f) - 8.f * (float)b)) *
                 0.5f);
  if (bi < 0) bi = 0;
  while ((bi + 1) * nt - ((bi + 1) * bi) / 2 <= b) ++bi;
  while (bi * nt - (bi * (bi - 1)) / 2 > b) --bi;
  int bj = bi + (b - (bi * nt - (bi * (bi - 1)) / 2));
  const int i0 = bi * 128, j0 = bj * 128;
  const bool offdiag = (bi != bj);

  const int t = threadIdx.x;
  const float4* Yg = (const float4*)Yh;
  for (int c = t; c < 128 * 16; c += 256) {
    int row = c >> 4, kc = c & 15;
    ((float4*)&As[row][0])[kc] = Yg[(size_t)(i0 + row) * 16 + kc];
    ((float4*)&Bs[row][0])[kc] = Yg[(size_t)(j0 + row) * 16 + kc];
  }
  if (t < 128) {
    labR[t] = lab[i0 + t];
    labC[t] = lab[j0 + t];
    rsumS[t] = 0.f;
    csumS[t] = 0.f;
  }
  if (t == 0) posCnt = 0;
  __syncthreads();

  const int w = t >> 6, lane = t & 63;
  const int quad = lane >> 4, l16 = lane & 15;
  const int rbase = (w >> 1) * 64, cbase = (w & 1) * 64;

  f32x4 acc[4][4] = {};
#pragma unroll
  for (int ks = 0; ks < 4; ++ks) {
    const int kof = ks * 32 + quad * 8;
    half8 af[4], bf[4];
#pragma unroll
    for (int p = 0; p < 4; ++p)
      af[p] = *(const half8*)&As[rbase + p * 16 + l16][kof];
#pragma unroll
    for (int p = 0; p < 4; ++p)
      bf[p] = *(const half8*)&Bs[cbase + p * 16 + l16][kof];
#pragma unroll
    for (int pi = 0; pi < 4; ++pi)
#pragma unroll
      for (int pj = 0; pj < 4; ++pj)
        acc[pi][pj] = __builtin_amdgcn_mfma_f32_16x16x32_f16(
            af[pi], bf[pj], acc[pi][pj], 0, 0, 0);
  }

  // ---- epilogue ----
  int lr[4][4], lc[4];
#pragma unroll
  for (int pi = 0; pi < 4; ++pi)
#pragma unroll
    for (int r = 0; r < 4; ++r) lr[pi][r] = labR[rbase + pi * 16 + quad * 4 + r];
#pragma unroll
  for (int pj = 0; pj < 4; ++pj) lc[pj] = labC[cbase + pj * 16 + l16];

  float rowp[4][4] = {};
  float colp[4] = {0.f, 0.f, 0.f, 0.f};
#pragma unroll
  for (int pi = 0; pi < 4; ++pi)
#pragma unroll
    for (int pj = 0; pj < 4; ++pj)
#pragma unroll
      for (int r = 0; r < 4; ++r) {
        const int gi = i0 + rbase + pi * 16 + quad * 4 + r;
        const int gj = j0 + cbase + pj * 16 + l16;
        const bool same = (lr[pi][r] == lc[pj]);
        float s = acc[pi][pj][r];
        // negatives -> unsim partial sums
        float e = same ? 0.f : __expf(s);
        rowp[pi][r] += e;
        colp[pj] += e;
        // positives -> record append
        bool pos = same && (gi != gj);
        unsigned long long mb = __ballot(pos);
        if (mb) {
          int cntb = __popcll(mb);
          int nadd = offdiag ? 2 * cntb : cntb;
          int leader = (int)__builtin_ctzll(mb);
          int base = 0;
          if (lane == leader) base = atomicAdd(&posCnt, nadd);
          base = __shfl(base, leader);
          if (pos) {
            int pref = (int)__popcll(mb & ((1ull << lane) - 1ull));
            unsigned sb = __float_as_uint(s);
            if (offdiag) {
              int s0 = base + 2 * pref;
              uint2 e0 = {(unsigned)gi, sb};
              uint2 e1 = {(unsigned)gj, sb};
              if (s0 < PCAP) posS[s0] = e0;
              else posBuf[atomicAdd(pcur, 1)] = e0;
              if (s0 + 1 < PCAP) posS[s0 + 1] = e1;
              else posBuf[atomicAdd(pcur, 1)] = e1;
            } else {
              int s0 = base + pref;
              uint2 e0 = {(unsigned)gi, sb};
              if (s0 < PCAP) posS[s0] = e0;
              else posBuf[atomicAdd(pcur, 1)] = e0;
            }
          }
        }
      }

  // row sums: reduce across the 16 lanes of each quad (cols)
#pragma unroll
  for (int pi = 0; pi < 4; ++pi)
#pragma unroll
    for (int r = 0; r < 4; ++r) {
      float v = rowp[pi][r];
      v += __shfl_xor(v, 1);
      v += __shfl_xor(v, 2);
      v += __shfl_xor(v, 4);
      v += __shfl_xor(v, 8);
      if (l16 == 0) atomicAdd(&rsumS[rbase + pi * 16 + quad * 4 + r], v);
    }
  // col sums: reduce across quads (rows)
#pragma unroll
  for (int pj = 0; pj < 4; ++pj) {
    float v = colp[pj];
    v += __shfl_xor(v, 16);
    v += __shfl_xor(v, 32);
    if (quad == 0) atomicAdd(&csumS[cbase + pj * 16 + l16], v);
  }
  __syncthreads();

  // flush unsim partials
  if (t < 128) {
    atomicAdd(&unsim[i0 + t], rsumS[t]);
  } else if (offdiag) {
    atomicAdd(&unsim[j0 + (t - 128)], csumS[t - 128]);
  }
  // flush positive records (LDS-staged part)
  int total = posCnt < PCAP ? posCnt : PCAP;
  if (t == 0) gbaseS = atomicAdd(pcur, total);
  __syncthreads();
  for (int e = t; e < total; e += 256) posBuf[gbaseS + e] = posS[e];
}

// ---------------------------------------------------------------------------
// Kernel 5: stream positive records: term = log(exp(s) + unsim[idx]) - s
__global__ __launch_bounds__(256) void pass3_kernel(
    const uint2* __restrict__ posBuf, const int* __restrict__ pcur,
    const float* __restrict__ unsim, float* __restrict__ accum) {
  int n = *pcur;
  float local = 0.f;
  int stride = 256 * gridDim.x;
  for (int p = blockIdx.x * 256 + threadIdx.x; p < n; p += stride) {
    uint2 e = posBuf[p];
    float s = __uint_as_float(e.y);
    local += logf(__expf(s) + unsim[e.x]) - s;
  }
  __shared__ float red[4];
#pragma unroll
  for (int msk = 1; msk < 64; msk <<= 1) local += __shfl_xor(local, msk);
  int lane = threadIdx.x & 63, w = threadIdx.x >> 6;
  if (lane == 0) red[w] = local;
  __syncthreads();
  if (threadIdx.x == 0) atomicAdd(&accum[0], red[0] + red[1] + red[2] + red[3]);
}

// Kernel 6: finalize
__global__ void finalize_kernel(const float* __restrict__ accum,
                                float* __restrict__ out) {
  out[0] = accum[0] / accum[1];
}

// ---------------------------------------------------------------------------
extern "C" void kernel_launch(void* const* d_in, const int* in_sizes, int n_in,
                              void* d_out, int out_size, void* d_ws,
                              size_t ws_size, hipStream_t stream) {
  const float* X = (const float*)d_in[0];
  const int* lab = (const int*)d_in[1];
  float* out = (float*)d_out;

  const int N = in_sizes[1];  // 8192; D fixed at 128

  // workspace layout
  _Float16* Yh = (_Float16*)d_ws;            // N*128 f16 (2 MB)
  float* unsim = (float*)(Yh + (size_t)N * 128);  // N f32
  float* accum = unsim + N;                  // 2 f32
  int* cnt = (int*)(accum + 2);              // NBINS
  int* pcur = cnt + NBINS;                   // 1
  uint2* posBuf = (uint2*)(pcur + 3);        // 8B-aligned; ~768k entries used

  // zero unsim + accum + cnt + pcur (contiguous)
  hipMemsetAsync(unsim, 0, (size_t)(N + 2 + NBINS + 3) * sizeof(float), stream);

  const float inv_sqrtT = 2.2360679775f;  // 1/sqrt(0.2)
  norm_kernel<<<N, 64, 0, stream>>>(X, Yh, inv_sqrtT);
  hist_kernel<<<(N + 255) / 256, 256, 0, stream>>>(lab, cnt, N);
  npos_kernel<<<1, 256, 0, stream>>>(cnt, accum, N);

  const int nt = N / 128;              // 64 tiles per dim
  const int nblk = nt * (nt + 1) / 2;  // 2080 upper-tri tile pairs
  pass1_kernel<<<nblk, 256, 0, stream>>>(Yh, lab, unsim, posBuf, pcur, nt);
  pass3_kernel<<<512, 256, 0, stream>>>(posBuf, pcur, unsim, accum);
  finalize_kernel<<<1, 1, 0, stream>>>(accum, out);
}

// Round 4
// 150.964 us; speedup vs baseline: 3.8393x; 1.1309x over previous
//
#include <hip/hip_runtime.h>
#include <math.h>

#define PCAP 1024  // per-block LDS positive-pair staging capacity

typedef _Float16 half8 __attribute__((ext_vector_type(8)));
typedef _Float16 half2v __attribute__((ext_vector_type(2)));
typedef float f32x4 __attribute__((ext_vector_type(4)));

// ---------------------------------------------------------------------------
// Kernel 1: row normalization. y_i = x_i / (||x_i|| * sqrt(T)), f16 output.
// 4 rows per 256-thread block (one row per wave).
__global__ __launch_bounds__(256) void norm_kernel(
    const float* __restrict__ X, _Float16* __restrict__ Yh, float inv_sqrtT) {
  int w = threadIdx.x >> 6, lane = threadIdx.x & 63;
  int row = blockIdx.x * 4 + w;
  float2 v = ((const float2*)(X + (size_t)row * 128))[lane];
  float s = v.x * v.x + v.y * v.y;
#pragma unroll
  for (int m = 1; m < 64; m <<= 1) s += __shfl_xor(s, m);
  float inv = inv_sqrtT * rsqrtf(fmaxf(s, 1e-24f));
  half2v h;
  h.x = (_Float16)(v.x * inv);
  h.y = (_Float16)(v.y * inv);
  ((half2v*)(Yh + (size_t)row * 128))[lane] = h;
}

// ---------------------------------------------------------------------------
// Kernel 2: MFMA similarity pass over upper-triangular 128x128 tile pairs.
// Fused: exp + label-mask row/col sums into unsim, AND positive-pair
// (idx, s) record append. Per-lane rare-path atomics (no ballot — positives
// are ~1/128 dense; the ballot machinery was the R3 bottleneck).
__global__ __launch_bounds__(256, 2) void pass1_kernel(
    const _Float16* __restrict__ Yh, const int* __restrict__ lab,
    float* __restrict__ unsim, uint2* __restrict__ posBuf,
    int* __restrict__ pcur, int nt) {
  __shared__ _Float16 As[128][136];  // +8 halves pad
  __shared__ _Float16 Bs[128][136];
  __shared__ int labR[128], labC[128];
  __shared__ float rsumS[128], csumS[128];
  __shared__ uint2 posS[PCAP];
  __shared__ int posCnt, gbaseS;

  // decode linear block id -> (bi, bj), bi <= bj
  int b = blockIdx.x;
  float ntf = (float)nt;
  int bi = (int)((2.f * ntf + 1.f -
                  sqrtf((2.f * ntf + 1.f) * (2.f * ntf + 1.f) - 8.f * (float)b)) *
                 0.5f);
  if (bi < 0) bi = 0;
  while ((bi + 1) * nt - ((bi + 1) * bi) / 2 <= b) ++bi;
  while (bi * nt - (bi * (bi - 1)) / 2 > b) --bi;
  int bj = bi + (b - (bi * nt - (bi * (bi - 1)) / 2));
  const int i0 = bi * 128, j0 = bj * 128;
  const bool offdiag = (bi != bj);

  const int t = threadIdx.x;
  const float4* Yg = (const float4*)Yh;
  for (int c = t; c < 128 * 16; c += 256) {
    int row = c >> 4, kc = c & 15;
    ((float4*)&As[row][0])[kc] = Yg[(size_t)(i0 + row) * 16 + kc];
    ((float4*)&Bs[row][0])[kc] = Yg[(size_t)(j0 + row) * 16 + kc];
  }
  if (t < 128) {
    labR[t] = lab[i0 + t];
    labC[t] = lab[j0 + t];
    rsumS[t] = 0.f;
    csumS[t] = 0.f;
  }
  if (t == 0) posCnt = 0;
  __syncthreads();

  const int w = t >> 6, lane = t & 63;
  const int quad = lane >> 4, l16 = lane & 15;
  const int rbase = (w >> 1) * 64, cbase = (w & 1) * 64;

  f32x4 acc[4][4] = {};
#pragma unroll
  for (int ks = 0; ks < 4; ++ks) {
    const int kof = ks * 32 + quad * 8;
    half8 af[4], bf[4];
#pragma unroll
    for (int p = 0; p < 4; ++p)
      af[p] = *(const half8*)&As[rbase + p * 16 + l16][kof];
#pragma unroll
    for (int p = 0; p < 4; ++p)
      bf[p] = *(const half8*)&Bs[cbase + p * 16 + l16][kof];
#pragma unroll
    for (int pi = 0; pi < 4; ++pi)
#pragma unroll
      for (int pj = 0; pj < 4; ++pj)
        acc[pi][pj] = __builtin_amdgcn_mfma_f32_16x16x32_f16(
            af[pi], bf[pj], acc[pi][pj], 0, 0, 0);
  }

  // ---- epilogue ----
  int lr[4][4], lc[4];
#pragma unroll
  for (int pi = 0; pi < 4; ++pi)
#pragma unroll
    for (int r = 0; r < 4; ++r) lr[pi][r] = labR[rbase + pi * 16 + quad * 4 + r];
#pragma unroll
  for (int pj = 0; pj < 4; ++pj) lc[pj] = labC[cbase + pj * 16 + l16];

  float rowp[4][4] = {};
  float colp[4] = {0.f, 0.f, 0.f, 0.f};
#pragma unroll
  for (int pi = 0; pi < 4; ++pi)
#pragma unroll
    for (int pj = 0; pj < 4; ++pj)
#pragma unroll
      for (int r = 0; r < 4; ++r) {
        const bool same = (lr[pi][r] == lc[pj]);
        float s = acc[pi][pj][r];
        float e = same ? 0.f : __expf(s);
        rowp[pi][r] += e;
        colp[pj] += e;
        if (same) {  // rare (~1/128): per-lane divergent path, no ballot
          const int gi = i0 + rbase + pi * 16 + quad * 4 + r;
          const int gj = j0 + cbase + pj * 16 + l16;
          if (offdiag || (gi != gj)) {
            int nadd = offdiag ? 2 : 1;
            int s0 = atomicAdd(&posCnt, nadd);
            unsigned sb = __float_as_uint(s);
            uint2 e0 = {(unsigned)gi, sb};
            if (s0 < PCAP) posS[s0] = e0;
            else posBuf[atomicAdd(pcur, 1)] = e0;
            if (offdiag) {
              uint2 e1 = {(unsigned)gj, sb};
              if (s0 + 1 < PCAP) posS[s0 + 1] = e1;
              else posBuf[atomicAdd(pcur, 1)] = e1;
            }
          }
        }
      }

  // row sums: reduce across the 16 lanes of each quad (cols)
#pragma unroll
  for (int pi = 0; pi < 4; ++pi)
#pragma unroll
    for (int r = 0; r < 4; ++r) {
      float v = rowp[pi][r];
      v += __shfl_xor(v, 1);
      v += __shfl_xor(v, 2);
      v += __shfl_xor(v, 4);
      v += __shfl_xor(v, 8);
      if (l16 == 0) atomicAdd(&rsumS[rbase + pi * 16 + quad * 4 + r], v);
    }
  // col sums: reduce across quads (rows)
#pragma unroll
  for (int pj = 0; pj < 4; ++pj) {
    float v = colp[pj];
    v += __shfl_xor(v, 16);
    v += __shfl_xor(v, 32);
    if (quad == 0) atomicAdd(&csumS[cbase + pj * 16 + l16], v);
  }
  __syncthreads();

  // flush unsim partials
  if (t < 128) {
    atomicAdd(&unsim[i0 + t], rsumS[t]);
  } else if (offdiag) {
    atomicAdd(&unsim[j0 + (t - 128)], csumS[t - 128]);
  }
  // flush positive records (LDS-staged part)
  int total = posCnt < PCAP ? posCnt : PCAP;
  if (t == 0) gbaseS = atomicAdd(pcur, total);
  __syncthreads();
  for (int e = t; e < total; e += 256) posBuf[gbaseS + e] = posS[e];
}

// ---------------------------------------------------------------------------
// Kernel 3: stream positive records: term = log(exp(s) + unsim[idx]) - s
__global__ __launch_bounds__(256) void pass3_kernel(
    const uint2* __restrict__ posBuf, const int* __restrict__ pcur,
    const float* __restrict__ unsim, float* __restrict__ accum) {
  int n = *pcur;
  float local = 0.f;
  int stride = 256 * gridDim.x;
  for (int p = blockIdx.x * 256 + threadIdx.x; p < n; p += stride) {
    uint2 e = posBuf[p];
    float s = __uint_as_float(e.y);
    local += logf(__expf(s) + unsim[e.x]) - s;
  }
  __shared__ float red[4];
#pragma unroll
  for (int msk = 1; msk < 64; msk <<= 1) local += __shfl_xor(local, msk);
  int lane = threadIdx.x & 63, w = threadIdx.x >> 6;
  if (lane == 0) red[w] = local;
  __syncthreads();
  if (threadIdx.x == 0) atomicAdd(&accum[0], red[0] + red[1] + red[2] + red[3]);
}

// Kernel 4: finalize. n_pos == number of appended ordered positive records.
__global__ void finalize_kernel(const float* __restrict__ accum,
                                const int* __restrict__ pcur,
                                float* __restrict__ out) {
  out[0] = accum[0] / (float)(*pcur);
}

// ---------------------------------------------------------------------------
extern "C" void kernel_launch(void* const* d_in, const int* in_sizes, int n_in,
                              void* d_out, int out_size, void* d_ws,
                              size_t ws_size, hipStream_t stream) {
  const float* X = (const float*)d_in[0];
  const int* lab = (const int*)d_in[1];
  float* out = (float*)d_out;

  const int N = in_sizes[1];  // 8192; D fixed at 128

  // workspace layout
  _Float16* Yh = (_Float16*)d_ws;                 // N*128 f16 (2 MB)
  float* unsim = (float*)(Yh + (size_t)N * 128);  // N f32
  float* accum = unsim + N;                       // 2 f32
  int* pcur = (int*)(accum + 2);                  // 1 (+1 pad)
  uint2* posBuf = (uint2*)(pcur + 2);             // 8B-aligned; ~516k entries

  // zero unsim + accum + pcur (contiguous)
  hipMemsetAsync(unsim, 0, (size_t)(N + 4) * sizeof(float), stream);

  const float inv_sqrtT = 2.2360679775f;  // 1/sqrt(0.2)
  norm_kernel<<<N / 4, 256, 0, stream>>>(X, Yh, inv_sqrtT);

  const int nt = N / 128;              // 64 tiles per dim
  const int nblk = nt * (nt + 1) / 2;  // 2080 upper-tri tile pairs
  pass1_kernel<<<nblk, 256, 0, stream>>>(Yh, lab, unsim, posBuf, pcur, nt);
  pass3_kernel<<<512, 256, 0, stream>>>(posBuf, pcur, unsim, accum);
  finalize_kernel<<<1, 1, 0, stream>>>(accum, pcur, out);
}